// Round 9
// baseline (277.979 us; speedup 1.0000x reference)
//
#include <hip/hip_runtime.h>

#define B_ 2
#define H_ 16
#define T_ 2048
#define D_ 1024
#define HD_ 64
#define NEG_HUGE (-3.402823466e38f)
#define QSCALE 0.18033688011112042f   // 0.125 * log2(e), folded into Q projection

typedef unsigned short u16;
typedef unsigned int u32;
typedef __attribute__((ext_vector_type(8))) short bf16x8;
typedef __attribute__((ext_vector_type(4))) float f32x4;

__device__ __forceinline__ u16 f2bf(float f) {
    u32 u = __builtin_bit_cast(u32, f);
    u += 0x7FFFu + ((u >> 16) & 1u);      // RNE
    return (u16)(u >> 16);
}

// pack 2 f32 -> 2 bf16 (round-half-up) in one v_perm_b32
__device__ __forceinline__ u32 pk2bf(float f0, float f1) {
    const u32 a0 = __builtin_bit_cast(u32, f0) + 0x8000u;
    const u32 a1 = __builtin_bit_cast(u32, f1) + 0x8000u;
    return __builtin_amdgcn_perm(a1, a0, 0x07060302u);
}

__device__ __forceinline__ uint2 pk4bf(f32x4 a) {
    uint2 r;
    r.x = pk2bf(a[0], a[1]);
    r.y = pk2bf(a[2], a[3]);
    return r;
}

__device__ __forceinline__ f32x4 mfma16(bf16x8 a, bf16x8 b, f32x4 c) {
    return __builtin_amdgcn_mfma_f32_16x16x32_bf16(a, b, c, 0, 0, 0);
}

// fp32 -> bf16 cast of concat [x(4M) | Wq(1M) | Wk(1M) | Wv(1M) | Wo(1M)] elems
__global__ __launch_bounds__(256) void to_bf16(
    const float* __restrict__ x,  const float* __restrict__ wq,
    const float* __restrict__ wk, const float* __restrict__ wv,
    const float* __restrict__ wo, u16* __restrict__ dst)
{
    const size_t g = ((size_t)blockIdx.x * 256 + threadIdx.x) * 8;
    const float* src; size_t off;
    if      (g < (size_t)(4u << 20)) { src = x;  off = g; }
    else if (g < (size_t)(5u << 20)) { src = wq; off = g - (size_t)(4u << 20); }
    else if (g < (size_t)(6u << 20)) { src = wk; off = g - (size_t)(5u << 20); }
    else if (g < (size_t)(7u << 20)) { src = wv; off = g - (size_t)(6u << 20); }
    else                             { src = wo; off = g - (size_t)(7u << 20); }
    const float4 a = *(const float4*)&src[off];
    const float4 b = *(const float4*)&src[off + 4];
    ushort4 lo = make_ushort4(f2bf(a.x), f2bf(a.y), f2bf(a.z), f2bf(a.w));
    ushort4 hi = make_ushort4(f2bf(b.x), f2bf(b.y), f2bf(b.z), f2bf(b.w));
    *(ushort4*)&dst[g]     = lo;
    *(ushort4*)&dst[g + 4] = hi;
}

// 128x128x1024 bf16 MFMA core with register-prefetch staging (no vmcnt(0)
// drain at barriers). NT: C = P0 · P1^T; acc[i][j]: M = wm+i*16+quad*4+r,
// N = wn+j*16+l15. LDS XOR-swizzled so ds_read_b128 fragments are 2-way.
__device__ __forceinline__ void gemm128_core(
    const u16* __restrict__ P0, const u16* __restrict__ P1,
    const int m0, const int n0, u16* As, u16* Bs, f32x4 (&acc)[4][4])
{
    const int tid  = threadIdx.x;
    const int lane = tid & 63;
    const int quad = lane >> 4;
    const int l15  = lane & 15;
    const int w    = tid >> 6;
    const int wm   = (w >> 1) << 6;
    const int wn   = (w & 1) << 6;
    const int swz  = l15 & 7;

    size_t aoff[4], boff[4];
    int    loff[4];
#pragma unroll
    for (int i = 0; i < 4; ++i) {
        const int slot = i * 256 + tid;
        const int r = slot >> 3, c = slot & 7;
        const int gc = (c ^ (r & 7)) << 3;
        aoff[i] = (size_t)(m0 + r) * D_ + gc;
        boff[i] = (size_t)(n0 + r) * D_ + gc;
        loff[i] = slot * 8;
    }
    int rowA[4], rowB[4];
#pragma unroll
    for (int i = 0; i < 4; ++i) {
        rowA[i] = (wm + i * 16 + l15) * 64;
        rowB[i] = (wn + i * 16 + l15) * 64;
    }

    bf16x8 pa[4], pb[4];
#pragma unroll
    for (int i = 0; i < 4; ++i) {
        pa[i] = *(const bf16x8*)&P0[aoff[i]];
        pb[i] = *(const bf16x8*)&P1[boff[i]];
    }

    for (int k0 = 0; k0 < D_; k0 += 64) {
        __syncthreads();
#pragma unroll
        for (int i = 0; i < 4; ++i) {
            *(bf16x8*)&As[loff[i]] = pa[i];
            *(bf16x8*)&Bs[loff[i]] = pb[i];
        }
        if (k0 + 64 < D_) {
            const int kn = k0 + 64;
#pragma unroll
            for (int i = 0; i < 4; ++i) {
                pa[i] = *(const bf16x8*)&P0[aoff[i] + kn];
                pb[i] = *(const bf16x8*)&P1[boff[i] + kn];
            }
        }
        __syncthreads();
#pragma unroll
        for (int s = 0; s < 2; ++s) {
            const int ch = (((s << 2) + quad) ^ swz) << 3;
            bf16x8 am[4], bm[4];
#pragma unroll
            for (int mi = 0; mi < 4; ++mi) am[mi] = *(const bf16x8*)&As[rowA[mi] + ch];
#pragma unroll
            for (int ni = 0; ni < 4; ++ni) bm[ni] = *(const bf16x8*)&Bs[rowB[ni] + ch];
#pragma unroll
            for (int mi = 0; mi < 4; ++mi)
#pragma unroll
                for (int ni = 0; ni < 4; ++ni)
                    acc[mi][ni] = mfma16(am[mi], bm[ni], acc[mi][ni]);
        }
    }
}

// Fused QKV projection (bf16 inputs). XCD-swizzled 1-D grid 768.
__global__ __launch_bounds__(256) void gemm_qkv(
    const u16* __restrict__ xb,
    const u16* __restrict__ Wqb, const u16* __restrict__ Wkb, const u16* __restrict__ Wvb,
    const float* __restrict__ bq, const float* __restrict__ bk, const float* __restrict__ bv,
    u16* __restrict__ Qb, u16* __restrict__ Kb, u16* __restrict__ Vtb)
{
    __shared__ u16 As[128 * 64];
    __shared__ u16 Bs[128 * 64];
    const int L   = blockIdx.x;
    const int xcd = L & 7;
    const int kk  = L >> 3;               // 0..95
    const int tt  = (xcd << 2) + (kk & 3);
    const int ft  = (kk >> 2) & 7;
    const int z   = kk >> 5;

    f32x4 acc[4][4];
#pragma unroll
    for (int i = 0; i < 4; ++i)
#pragma unroll
        for (int j = 0; j < 4; ++j) acc[i][j] = (f32x4){0.f, 0.f, 0.f, 0.f};

    const int tid  = threadIdx.x;
    const int lane = tid & 63;
    const int quad = lane >> 4;
    const int l15  = lane & 15;
    const int w    = tid >> 6;
    const int wm   = (w >> 1) << 6;
    const int wn   = (w & 1) << 6;
    const int pq   = quad >> 1;
    const int psub = (quad & 1) << 2;

    u16* scr = ((w < 2) ? As : Bs) + ((w & 1) ? 4096 : 0);   // 8KB per wave

    if (z < 2) {
        const u16*   W    = z ? Wkb : Wqb;
        const float* bias = z ? bk  : bq;
        const float  CF   = z ? 1.f : QSCALE;
        u16*         C    = z ? Kb  : Qb;
        const int m0 = ft << 7;
        const int n0 = tt << 7;
        gemm128_core(W, xb, m0, n0, As, Bs, acc);
        __syncthreads();

        const int fb = m0 + wm;
        const int h  = fb >> 6;
        const int tb = n0 + wn;
#pragma unroll
        for (int i = 0; i < 4; ++i) {
            const float4 bi = *(const float4*)&bias[fb + i * 16 + (quad << 2)];
#pragma unroll
            for (int j = 0; j < 4; ++j) {
                const int tl = j * 16 + l15;
                f32x4 a = acc[i][j];
                f32x4 v = { (a[0] + bi.x) * CF, (a[1] + bi.y) * CF,
                            (a[2] + bi.z) * CF, (a[3] + bi.w) * CF };
                *(uint2*)&scr[tl * 64 + (((2 * i + pq) ^ (tl & 7)) << 3) + psub] = pk4bf(v);
            }
        }
        __asm__ volatile("s_waitcnt lgkmcnt(0)" ::: "memory");

        const int b  = tb >> 11;
        const int t0 = tb & 2047;
#pragma unroll
        for (int e = 0; e < 8; ++e) {
            const int tl = (lane >> 3) + e * 8;
            const int c  = lane & 7;
            bf16x8 v = *(const bf16x8*)&scr[tl * 64 + ((c ^ (tl & 7)) << 3)];
            *(bf16x8*)&C[((size_t)((b << 4) + h) * T_ + t0 + tl) * HD_ + (c << 3)] = v;
        }
    } else {
        const int m0 = tt << 7;
        const int n0 = ft << 7;
        gemm128_core(xb, Wvb, m0, n0, As, Bs, acc);
        __syncthreads();

#pragma unroll
        for (int j = 0; j < 4; ++j) {
            const int row = j * 16 + l15;
            const float bi = bv[n0 + wn + row];
            const int sw = row & 7;
#pragma unroll
            for (int i = 0; i < 4; ++i) {
                f32x4 a = acc[i][j];
                f32x4 v = { a[0] + bi, a[1] + bi, a[2] + bi, a[3] + bi };
                *(uint2*)&scr[row * 64 + (((2 * i + pq) ^ sw) << 3) + psub] = pk4bf(v);
            }
        }
        __asm__ volatile("s_waitcnt lgkmcnt(0)" ::: "memory");

        const int b  = (m0 + wm) >> 11;
        const int t0 = (m0 + wm) & 2047;
        const int h  = (n0 + wn) >> 6;
#pragma unroll
        for (int e = 0; e < 8; ++e) {
            const int hdl = (lane >> 3) + e * 8;
            const int c   = lane & 7;
            bf16x8 vv = *(const bf16x8*)&scr[hdl * 64 + ((c ^ (hdl & 7)) << 3)];
            *(bf16x8*)&Vtb[((size_t)((b << 4) + h) * HD_ + hdl) * T_ + t0 + (c << 3)] = vv;
        }
    }
}

// Output projection: A bf16 (B,T,D), W bf16, C fp32 + bias. XCD-swizzled.
__global__ __launch_bounds__(256) void gemm_out(
    const u16* __restrict__ Ab, const u16* __restrict__ Wob,
    const float* __restrict__ bo, float* __restrict__ C)
{
    __shared__ u16 As[128 * 64];
    __shared__ u16 Bs[128 * 64];
    const int L   = blockIdx.x;
    const int xcd = L & 7;
    const int kk  = L >> 3;
    const int tt  = (xcd << 2) + (kk & 3);
    const int ft  = kk >> 2;
    const int m0  = tt << 7;
    const int n0  = ft << 7;

    f32x4 acc[4][4];
#pragma unroll
    for (int i = 0; i < 4; ++i)
#pragma unroll
        for (int j = 0; j < 4; ++j) acc[i][j] = (f32x4){0.f, 0.f, 0.f, 0.f};

    gemm128_core(Ab, Wob, m0, n0, As, Bs, acc);

    const int tid  = threadIdx.x;
    const int lane = tid & 63;
    const int quad = lane >> 4;
    const int l15  = lane & 15;
    const int w    = tid >> 6;
    const int wm   = (w >> 1) << 6;
    const int wn   = (w & 1) << 6;

    float bi[4];
#pragma unroll
    for (int ni = 0; ni < 4; ++ni) bi[ni] = bo[n0 + wn + ni * 16 + l15];

#pragma unroll
    for (int mi = 0; mi < 4; ++mi) {
        const int m = m0 + wm + mi * 16 + (quad << 2);
#pragma unroll
        for (int r = 0; r < 4; ++r)
#pragma unroll
            for (int ni = 0; ni < 4; ++ni)
                C[(size_t)(m + r) * D_ + n0 + wn + ni * 16 + l15] = acc[mi][ni][r] + bi[ni];
    }
}

// Barrier-free MFMA flash attention. One wave = one 16-row q-tile walking
// its causal key range in 64-key steps. Max-free base-2 softmax (additive
// partials) means waves never communicate: K/V fragments load DIRECTLY from
// global (L2-resident; K rows 128B fully coalesced), only P round-trips
// through a private 2KB LDS slice (lgkmcnt wait, no __syncthreads anywhere).
// Grid 1024 blocks: bh = id&31 pins each head's blocks to XCD bh%8 (K/V L2
// reuse); lb = id>>5 ascending = longest q-tiles dispatched first (LPT).
__global__ __launch_bounds__(256) void attn_mfma(
    const u16* __restrict__ Qg, const u16* __restrict__ Kg,
    const u16* __restrict__ Vtg, u16* __restrict__ Out)
{
    __shared__ u16 Ps[4 * 16 * 64];   // per-wave P [q16][key64], XOR-swizzled
    const int tid  = threadIdx.x;
    const int w    = tid >> 6;
    const int lane = tid & 63;
    const int quad = lane >> 4;
    const int l15  = lane & 15;
    const int id   = blockIdx.x;
    const int bh   = id & 31;
    const int lb   = id >> 5;                    // 0..31
    const int j    = 127 - ((lb << 2) + w);      // q16 tile 127..0 (LPT)
    const size_t base = (size_t)bh * (T_ * HD_);

    const int qrow = (j << 4) + l15;
    const bf16x8 qf0 = *(const bf16x8*)&Qg[base + (size_t)qrow * HD_ + quad * 8];
    const bf16x8 qf1 = *(const bf16x8*)&Qg[base + (size_t)qrow * HD_ + 32 + quad * 8];

    f32x4 o[4];
#pragma unroll
    for (int nt = 0; nt < 4; ++nt) o[nt] = (f32x4){0.f, 0.f, 0.f, 0.f};
    f32x4 Lacc = (f32x4){0.f, 0.f, 0.f, 0.f};

    const int nIter = (j >> 2) + 1;
    const int jm    = j & 3;

    bf16x8 ones;
#pragma unroll
    for (int i = 0; i < 8; ++i) ones[i] = (short)0x3F80;   // bf16 1.0

    u16* Pw = &Ps[w * 1024];
    const int swz  = l15 & 7;
    const int pq   = quad >> 1;
    const int psub = (quad & 1) << 2;

    // lane-fixed global offsets
    size_t kadr[4][2], vadr[4][2];
#pragma unroll
    for (int t = 0; t < 4; ++t)
#pragma unroll
        for (int c = 0; c < 2; ++c) {
            kadr[t][c] = base + (size_t)(t * 16 + l15) * HD_ + c * 32 + quad * 8;
            vadr[t][c] = base + (size_t)(t * 16 + l15) * T_  + c * 32 + quad * 8;
        }

    bf16x8 kf[4][2];
#pragma unroll
    for (int t = 0; t < 4; ++t)
#pragma unroll
        for (int c = 0; c < 2; ++c)
            kf[t][c] = *(const bf16x8*)&Kg[kadr[t][c]];

    // fixed diagonal-tile mask: key-local (quad*4+r) > l15
    bool mcond[4];
#pragma unroll
    for (int r = 0; r < 4; ++r) mcond[r] = ((quad << 2) + r) > l15;

    for (int it = 0; it < nIter; ++it) {
        const bool last = (it == nIter - 1);
        const int  tmax = last ? jm : 3;

        // S^T tiles (A = K rows, B = Q): st[t][r] = S[key=64it+16t+4quad+r][q=l15]
        f32x4 st[4];
#pragma unroll
        for (int t = 0; t < 4; ++t) {
            if (t <= tmax) {
                f32x4 a = (f32x4){0.f, 0.f, 0.f, 0.f};
                a = mfma16(kf[t][0], qf0, a);
                a = mfma16(kf[t][1], qf1, a);
                st[t] = a;
            }
        }

        if (!last) {
            const size_t koff = (size_t)(it + 1) * 64 * HD_;
#pragma unroll
            for (int t = 0; t < 4; ++t)
#pragma unroll
                for (int c = 0; c < 2; ++c)
                    kf[t][c] = *(const bf16x8*)&Kg[kadr[t][c] + koff];
        }

        uint2 px[4];
#pragma unroll
        for (int t = 0; t < 4; ++t) {
            if (t <= tmax) {
                if (last && t == jm) {
#pragma unroll
                    for (int r = 0; r < 4; ++r)
                        if (mcond[r]) st[t][r] = NEG_HUGE;
                }
#pragma unroll
                for (int r = 0; r < 4; ++r) st[t][r] = exp2f(st[t][r]);
                px[t] = pk4bf(st[t]);
            } else {
                px[t] = make_uint2(0u, 0u);
            }
        }

        // P (C-layout) -> private LDS [q][key], swizzled
#pragma unroll
        for (int t = 0; t < 4; ++t)
            *(uint2*)&Pw[l15 * 64 + ((((t << 1) + pq) ^ swz) << 3) + psub] = px[t];

        // V fragments from global (issued before the lgkm wait so their
        // latency overlaps the P round-trip)
        bf16x8 vf[4][2];
        const size_t voff = (size_t)it * 64;
#pragma unroll
        for (int nt = 0; nt < 4; ++nt)
#pragma unroll
            for (int c = 0; c < 2; ++c)
                vf[nt][c] = *(const bf16x8*)&Vtg[vadr[nt][c] + voff];

        __asm__ volatile("s_waitcnt lgkmcnt(0)" ::: "memory");

        bf16x8 pf[2];
#pragma unroll
        for (int c = 0; c < 2; ++c)
            pf[c] = *(const bf16x8*)&Pw[l15 * 64 + ((((c << 2) + quad) ^ swz) << 3)];

#pragma unroll
        for (int nt = 0; nt < 4; ++nt) {
            f32x4 oo = o[nt];
            oo = mfma16(pf[0], vf[nt][0], oo);
            oo = mfma16(pf[1], vf[nt][1], oo);
            o[nt] = oo;
        }
        Lacc = mfma16(pf[0], ones, Lacc);
        Lacc = mfma16(pf[1], ones, Lacc);
    }

    f32x4 linv;
#pragma unroll
    for (int r = 0; r < 4; ++r) linv[r] = 1.f / fmaxf(Lacc[r], 1e-30f);

    const int b = bh >> 4, h = bh & 15;
#pragma unroll
    for (int nt = 0; nt < 4; ++nt)
#pragma unroll
        for (int r = 0; r < 4; ++r) {
            const int qg2 = (j << 4) + (quad << 2) + r;
            const u32 u = __builtin_bit_cast(u32, o[nt][r] * linv[r]) + 0x8000u;
            Out[(size_t)(b * T_ + qg2) * D_ + (h << 6) + nt * 16 + l15] = (u16)(u >> 16);
        }
}

extern "C" void kernel_launch(void* const* d_in, const int* in_sizes, int n_in,
                              void* d_out, int out_size, void* d_ws, size_t ws_size,
                              hipStream_t stream)
{
    const float* x  = (const float*)d_in[0];
    // d_in[1]: causal mask (deterministic tril) — applied analytically.
    const float* Wq = (const float*)d_in[2];
    const float* bq = (const float*)d_in[3];
    const float* Wk = (const float*)d_in[4];
    const float* bk = (const float*)d_in[5];
    const float* Wv = (const float*)d_in[6];
    const float* bv = (const float*)d_in[7];
    const float* Wo = (const float*)d_in[8];
    const float* bo = (const float*)d_in[9];
    float* out = (float*)d_out;

    const size_t M1 = (size_t)1 << 20;
    u16* wsu = (u16*)d_ws;
    u16* xb  = wsu;             // 4M elems (B,T,D) bf16
    u16* wqb = wsu + 4 * M1;
    u16* wkb = wsu + 5 * M1;
    u16* wvb = wsu + 6 * M1;
    u16* wob = wsu + 7 * M1;
    u16* Qb  = wsu + 8 * M1;    // (B,H,T,HD) bf16, pre-scaled
    u16* Kb  = wsu + 12 * M1;   // (B,H,T,HD) bf16
    u16* Vtb = wsu + 16 * M1;   // (B,H,HD,T) bf16
    u16* AOb = wsu + 20 * M1;   // (B,T,D) bf16

    to_bf16<<<4096, 256, 0, stream>>>(x, Wq, Wk, Wv, Wo, wsu);

    gemm_qkv<<<768, 256, 0, stream>>>(xb, wqb, wkb, wvb, bq, bk, bv, Qb, Kb, Vtb);

    attn_mfma<<<1024, 256, 0, stream>>>(Qb, Kb, Vtb, AOb);

    gemm_out<<<256, 256, 0, stream>>>(AOb, wob, bo, out);
}